// Round 4
// baseline (149.787 us; speedup 1.0000x reference)
//
#include <hip/hip_runtime.h>
#include <hip/hip_bf16.h>

// KGATPGExp: out[e] = sigmoid( logit(noise[e]) + MLP(concat(emb[col],emb[row],emb[src],emb[dst])) )
// Decomposition (validated R2+, absmax 3.9e-3 vs thr 2e-2):
//   c[64]   = b1 + emb[src]@W1[256:384] + emb[dst]@W1[384:512]          (edge-invariant)
//   F[n][:] = emb[n]@W1[0:128] + c       (bf16, per node)   } fg_kernel (MFMA, HBM-bound)
//   G[n][:] = emb[n]@W1[128:256]         (bf16, per node)   }
//   out[e]  = sigmoid(logit(noise) + b2 + W2 . relu(F[col[e]] + G[row[e]]))   (edge_kernel)
// R4: cooperative fusion + per-thread fences = L2 wbinv storm (290us @ 4% HBM). Reverted.
// R5: one-thread-per-edge gathers: 32x request rate, only 1.8x time. Reverted.
// R6: fg launch_bounds(256,4): 128-VGPR cap -> spills. Keep (256,3).
// R7: 4-octet/wave batched edge: +9us (drain-point batching). Reverted.
// R8: R3 edge restore — 1 octet/wave, 12500 blocks. Best verified shape.
// R9: rolling 2-deep pipeline + persistent 2048 blocks: NULL. Edge not wave-latency-bound.
// R11: fp8 e4m3 tables (bytes AND line-transactions halved): NULL (-1.5us = noise),
//      absmax 1.95e-2 = 97.7% of gate. Third orthogonal null on edge.
// MODEL (R12): harness poison-fill writes 268MB at 80% HBM peak before each iter,
//      leaving LLC (256MB) full of dirty lines; our kernels run against a fixed
//      ~43us writeback drain + 41us fill. Edge/fg changes shuffle work under a
//      fixed memory-system cost -> all nulls. Remaining lever: don't pollute.
// R12 (this): revert tables to bf16 (restore 5x absmax margin — fp8 was risk for
//      noise), keep pair-packed epilogue + R8 edge; embed stream in fg via
//      non-temporal loads (51.2MB read-once; skip LLC allocation/churn).

typedef __bf16 bf16x8 __attribute__((ext_vector_type(8)));
typedef float  f32x16 __attribute__((ext_vector_type(16)));
typedef float  f32x4  __attribute__((ext_vector_type(4)));
typedef unsigned short u16;

#define WSTR 264   // sW row stride (u16): 256 + 8 pad
#define Z16 {0.f,0.f,0.f,0.f,0.f,0.f,0.f,0.f,0.f,0.f,0.f,0.f,0.f,0.f,0.f,0.f}

__device__ __forceinline__ unsigned bfbits(float f){       // fp32 -> bf16 bits, RNE
  unsigned u = __builtin_bit_cast(unsigned, f);
  return (u + 0x7fffu + ((u >> 16) & 1u)) >> 16;
}
__device__ __forceinline__ unsigned pk2(float a, float b){ // pack 2 fp32 -> bf16x2 bits
  return bfbits(a) | (bfbits(b) << 16);
}
__device__ __forceinline__ float bflo(unsigned u){ return __builtin_bit_cast(float, u << 16); }
__device__ __forceinline__ float bfhi(unsigned u){ return __builtin_bit_cast(float, u & 0xffff0000u); }

// ---------------------------------------------------------------------------
// fg: F = emb@W1a + c, G = emb@W1b over all nodes. One 32-node tile per wave,
// 4 waves (128 nodes) per block. Per-block prologue builds the bf16 transposed
// W1[0:256] in LDS and the c vector (both from L2-hot W1).
//   A (emb rows, streamed NT):  lane holds A[m=lane&31][k=(lane>>5)*8+j]
//   B (sW from LDS):            lane holds B[k=(lane>>5)*8+j][n=lane&31]
//   C/D:                        col(n)=lane&31, row(m)=(r&3)+8*(r>>2)+4*(lane>>5)
// launch_bounds(256,3): 170-VGPR budget — (256,4) caps at 128 and spills (R6 lesson).
__global__ __launch_bounds__(256, 3) void fg_kernel(
    const float* __restrict__ embed, const float* __restrict__ W1,
    const float* __restrict__ b1, const int* __restrict__ srcp,
    const int* __restrict__ dstp, u16* __restrict__ F, u16* __restrict__ G, int NN)
{
  __shared__ __align__(16) u16 sW[64 * WSTR];
  __shared__ float sC[64];
  __shared__ float sRed[256];
  int tid = threadIdx.x;

  // --- prologue A: transpose W1[0:256][0:64] fp32 -> sW[n][k] bf16 (L2-hot) ---
  #pragma unroll
  for (int i = 0; i < 16; ++i){
    int idx = i * 256 + tid;               // 4096 float4 reads, fully coalesced
    int k = idx >> 4, q = idx & 15;
    float4 v = *(const float4*)(W1 + k * 64 + q * 4);
    sW[(4*q+0) * WSTR + k] = (u16)bfbits(v.x);
    sW[(4*q+1) * WSTR + k] = (u16)bfbits(v.y);
    sW[(4*q+2) * WSTR + k] = (u16)bfbits(v.z);
    sW[(4*q+3) * WSTR + k] = (u16)bfbits(v.w);
  }
  // --- prologue B: c partials, 4-way k-split across the block ---
  {
    int h = tid & 63, part = tid >> 6;
    int si = srcp[0], di = dstp[0];
    const float* se  = embed + (size_t)si * 128 + part * 32;
    const float* de  = embed + (size_t)di * 128 + part * 32;
    const float* w1s = W1 + (256 + part * 32) * 64 + h;
    const float* w1d = W1 + (384 + part * 32) * 64 + h;
    float acc = 0.f;
    #pragma unroll 8
    for (int k = 0; k < 32; ++k){
      acc += se[k] * w1s[k * 64];
      acc += de[k] * w1d[k * 64];
    }
    sRed[tid] = acc;
  }
  __syncthreads();
  if (tid < 64) sC[tid] = b1[tid] + sRed[tid] + sRed[64+tid] + sRed[128+tid] + sRed[192+tid];
  __syncthreads();

  // --- main MFMA loop ---
  int lane = tid & 63, wave = tid >> 6;
  int nl = lane & 31, h5 = lane >> 5;
  int tile = blockIdx.x * 128 + wave * 32;
  if (tile >= NN) return;                      // NN % 32 == 0; barriers already passed
  const f32x4* erow = (const f32x4*)(embed + (size_t)(tile + nl) * 128);
  f32x16 aF0 = Z16, aF1 = Z16, aG0 = Z16, aG1 = Z16;
  const u16* sw0 = sW + nl * WSTR;             // hidden rows 0..31
  const u16* sw1 = sW + (32 + nl) * WSTR;      // hidden rows 32..63
  #pragma unroll
  for (int s = 0; s < 8; ++s){                 // K = 128, 16 per MFMA
    int ko = s * 16 + h5 * 8;
    f32x4 x = __builtin_nontemporal_load(erow + (ko >> 2));      // read-once stream:
    f32x4 y = __builtin_nontemporal_load(erow + (ko >> 2) + 1);  // skip LLC allocation
    uint4 u; u.x = pk2(x[0],x[1]); u.y = pk2(x[2],x[3]); u.z = pk2(y[0],y[1]); u.w = pk2(y[2],y[3]);
    bf16x8 a = __builtin_bit_cast(bf16x8, u);
    bf16x8 bF0 = *(const bf16x8*)(sw0 + ko);
    bf16x8 bF1 = *(const bf16x8*)(sw1 + ko);
    bf16x8 bG0 = *(const bf16x8*)(sw0 + 128 + ko);   // W1b at k=128..255
    bf16x8 bG1 = *(const bf16x8*)(sw1 + 128 + ko);
    aF0 = __builtin_amdgcn_mfma_f32_32x32x16_bf16(a, bF0, aF0, 0, 0, 0);
    aF1 = __builtin_amdgcn_mfma_f32_32x32x16_bf16(a, bF1, aF1, 0, 0, 0);
    aG0 = __builtin_amdgcn_mfma_f32_32x32x16_bf16(a, bG0, aG0, 0, 0, 0);
    aG1 = __builtin_amdgcn_mfma_f32_32x32x16_bf16(a, bG1, aG1, 0, 0, 0);
  }
  // --- epilogue: shfl_xor pair-pack cols; lane parity picks row r / r+1.
  // 4 u32 stores per r-pair (256B/instr across wave), bit-identical to scalar.
  float cv0 = sC[nl], cv1 = sC[32 + nl];
  int lo = lane & 1;
  int nlp = nl & ~1;                           // paired col base (u16 units)
  #pragma unroll
  for (int r = 0; r < 16; r += 2){
    int ra = r + lo;                           // row this lane stores
    int node = tile + (ra & 3) + 8 * (ra >> 2) + 4 * h5;
    u16* fr = F + (size_t)node * 64 + nlp;
    u16* gr = G + (size_t)node * 64 + nlp;
    float f0a = aF0[r]   + cv0;
    float f0b = aF0[r+1] + cv0;
    float f0an = __shfl_xor(f0a, 1), f0bn = __shfl_xor(f0b, 1);
    *(unsigned*)(fr)      = lo ? pk2(f0bn, f0b) : pk2(f0a, f0an);
    float f1a = aF1[r]   + cv1;
    float f1b = aF1[r+1] + cv1;
    float f1an = __shfl_xor(f1a, 1), f1bn = __shfl_xor(f1b, 1);
    *(unsigned*)(fr + 32) = lo ? pk2(f1bn, f1b) : pk2(f1a, f1an);
    float g0a = aG0[r], g0b = aG0[r+1];
    float g0an = __shfl_xor(g0a, 1), g0bn = __shfl_xor(g0b, 1);
    *(unsigned*)(gr)      = lo ? pk2(g0bn, g0b) : pk2(g0a, g0an);
    float g1a = aG1[r], g1b = aG1[r+1];
    float g1an = __shfl_xor(g1a, 1), g1bn = __shfl_xor(g1b, 1);
    *(unsigned*)(gr + 32) = lo ? pk2(g1bn, g1b) : pk2(g1a, g1an);
  }
}

// ---------------------------------------------------------------------------
// edge (R8 shape): 8 lanes per edge, lane j reads 16 B chunk j of the 128 B F/G
// row (8 merged line-requests per gather instruction). ONE octet per wave, no
// loop — 50K waves of minimal work; TLP hides the gather latency.
__global__ __launch_bounds__(256, 8) void edge_kernel(
    const u16* __restrict__ Ft, const u16* __restrict__ Gt,
    const float* __restrict__ W2, const float* __restrict__ b2,
    const float* __restrict__ noise, const int* __restrict__ col,
    const int* __restrict__ row, float* __restrict__ out, int E)
{
  int tid = threadIdx.x;
  int lane = tid & 63, wave = tid >> 6;
  int j = lane & 7, grp = lane >> 3;
  int e0 = blockIdx.x * 32 + wave * 8;
  if (e0 >= E) return;                         // wave-uniform
  int e = e0 + grp; if (e >= E) e = E - 1;     // clamp (safe read), store masked below
  int ci = col[e], ri = row[e];
  uint4 fv = ((const uint4*)(Ft + (size_t)ci * 64))[j];
  uint4 gv = ((const uint4*)(Gt + (size_t)ri * 64))[j];
  float4 w2a = ((const float4*)W2)[2 * j];
  float4 w2b = ((const float4*)W2)[2 * j + 1];
  float p = 0.f, h;
  h = fmaxf(bflo(fv.x) + bflo(gv.x), 0.f); p += h * w2a.x;
  h = fmaxf(bfhi(fv.x) + bfhi(gv.x), 0.f); p += h * w2a.y;
  h = fmaxf(bflo(fv.y) + bflo(gv.y), 0.f); p += h * w2a.z;
  h = fmaxf(bfhi(fv.y) + bfhi(gv.y), 0.f); p += h * w2a.w;
  h = fmaxf(bflo(fv.z) + bflo(gv.z), 0.f); p += h * w2b.x;
  h = fmaxf(bfhi(fv.z) + bfhi(gv.z), 0.f); p += h * w2b.y;
  h = fmaxf(bflo(fv.w) + bflo(gv.w), 0.f); p += h * w2b.z;
  h = fmaxf(bfhi(fv.w) + bfhi(gv.w), 0.f); p += h * w2b.w;
  p += __shfl_xor(p, 1, 64);
  p += __shfl_xor(p, 2, 64);
  p += __shfl_xor(p, 4, 64);
  if (j == 0 && e0 + grp < E){
    float ns = noise[e];
    float g = logf(ns) - log1pf(-ns) + p + b2[0];
    out[e] = 1.f / (1.f + expf(-g));
  }
}

// ---------------------------------------------------------------------------
// Insurance path if ws_size is too small for F/G tables: correct-but-slow fp32.
__global__ void naive_kernel(const float* __restrict__ embed, const float* __restrict__ W1,
    const float* __restrict__ b1, const float* __restrict__ W2, const float* __restrict__ b2,
    const float* __restrict__ noise, const int* __restrict__ col, const int* __restrict__ row,
    const int* __restrict__ srcp, const int* __restrict__ dstp, float* __restrict__ out, int E)
{
  int e = blockIdx.x * 256 + threadIdx.x;
  if (e >= E) return;
  int ci = col[e], ri = row[e], si = srcp[0], di = dstp[0];
  const float* ce = embed + (size_t)ci * 128;
  const float* re = embed + (size_t)ri * 128;
  const float* se = embed + (size_t)si * 128;
  const float* de = embed + (size_t)di * 128;
  float w = b2[0];
  for (int jj = 0; jj < 64; ++jj){
    float hh = b1[jj];
    for (int k = 0; k < 128; ++k){
      hh += ce[k] * W1[k * 64 + jj] + re[k] * W1[(128 + k) * 64 + jj]
          + se[k] * W1[(256 + k) * 64 + jj] + de[k] * W1[(384 + k) * 64 + jj];
    }
    w += fmaxf(hh, 0.f) * W2[jj];
  }
  float ns = noise[e];
  float g = logf(ns) - log1pf(-ns) + w;
  out[e] = 1.f / (1.f + expf(-g));
}

// ---------------------------------------------------------------------------
extern "C" void kernel_launch(void* const* d_in, const int* in_sizes, int n_in,
                              void* d_out, int out_size, void* d_ws, size_t ws_size,
                              hipStream_t stream)
{
  const float* embed = (const float*)d_in[0];
  const float* W1    = (const float*)d_in[1];
  const float* b1    = (const float*)d_in[2];
  const float* W2    = (const float*)d_in[3];
  const float* b2    = (const float*)d_in[4];
  const float* noise = (const float*)d_in[5];
  const int*   col   = (const int*)d_in[6];
  const int*   rowp  = (const int*)d_in[7];
  const int*   srcp  = (const int*)d_in[8];
  const int*   dstp  = (const int*)d_in[9];
  const int E  = in_sizes[5];
  const int NN = in_sizes[0] / 128;
  float* out = (float*)d_out;

  const size_t fBytes = (size_t)NN * 64 * sizeof(u16);
  if (ws_size >= 2 * fBytes){
    u16* F = (u16*)d_ws;
    u16* G = (u16*)((char*)d_ws + fBytes);
    fg_kernel<<<(NN + 127) / 128, 256, 0, stream>>>(embed, W1, b1, srcp, dstp, F, G, NN);
    edge_kernel<<<(E + 31) / 32, 256, 0, stream>>>(F, G, W2, b2, noise, col, rowp, out, E);
  } else {
    naive_kernel<<<(E + 255) / 256, 256, 0, stream>>>(embed, W1, b1, W2, b2, noise,
                                                      col, rowp, srcp, dstp, out, E);
  }
}

// Round 5
// 139.415 us; speedup vs baseline: 1.0744x; 1.0744x over previous
//
#include <hip/hip_runtime.h>
#include <hip/hip_bf16.h>

// KGATPGExp: out[e] = sigmoid( logit(noise[e]) + MLP(concat(emb[col],emb[row],emb[src],emb[dst])) )
// Decomposition (validated R2+, absmax 3.9e-3 vs thr 2e-2):
//   c[64]   = b1 + emb[src]@W1[256:384] + emb[dst]@W1[384:512]          (edge-invariant)
//   F[n][:] = emb[n]@W1[0:128] + c       (bf16, per node)   } fg_kernel (MFMA, HBM-bound)
//   G[n][:] = emb[n]@W1[128:256]         (bf16, per node)   }
//   out[e]  = sigmoid(logit(noise) + b2 + W2 . relu(F[col[e]] + G[row[e]]))   (edge_kernel)
// R4: cooperative fusion + per-thread fences = L2 wbinv storm (290us @ 4% HBM). Reverted.
// R5: one-thread-per-edge gathers: 32x request rate, only 1.8x time. Reverted.
// R6: fg launch_bounds(256,4): 128-VGPR cap -> spills. Keep (256,3).
// R7: 4-octet/wave batched edge: +9us (drain-point batching). Reverted.
// R8: R3 edge restore — 1 octet/wave, 12500 blocks. Best verified shape.
// R9: rolling 2-deep pipeline + persistent 2048 blocks: NULL. Edge not wave-latency-bound.
// R11: fp8 e4m3 tables (bytes AND transactions halved): NULL, absmax 97.7% of gate.
// R12: fg embed stream via non-temporal loads: +14us REGRESSION. Each 128B line is
//      consumed by two 64B loads across K-iters; NT no-allocate turns the second
//      into a fresh memory fetch -> ~2x stream traffic. Reverted.
// MODEL (confirmed by R7/R9/R11 nulls + R12 mechanism): harness poison-fill writes
//      268MB at ~80% HBM peak each iter; kernels run against that fixed drain +
//      51MB embed read + LLC-resident gather floor. Addressable headroom is noise.
// R13 (this): pure revert of R12's NT loads — best verified config restored
//      (bf16 tables + pair-packed fg epilogue + R8 edge). Confirmation run.

typedef __bf16 bf16x8 __attribute__((ext_vector_type(8)));
typedef float  f32x16 __attribute__((ext_vector_type(16)));
typedef unsigned short u16;

#define WSTR 264   // sW row stride (u16): 256 + 8 pad
#define Z16 {0.f,0.f,0.f,0.f,0.f,0.f,0.f,0.f,0.f,0.f,0.f,0.f,0.f,0.f,0.f,0.f}

__device__ __forceinline__ unsigned bfbits(float f){       // fp32 -> bf16 bits, RNE
  unsigned u = __builtin_bit_cast(unsigned, f);
  return (u + 0x7fffu + ((u >> 16) & 1u)) >> 16;
}
__device__ __forceinline__ unsigned pk2(float a, float b){ // pack 2 fp32 -> bf16x2 bits
  return bfbits(a) | (bfbits(b) << 16);
}
__device__ __forceinline__ float bflo(unsigned u){ return __builtin_bit_cast(float, u << 16); }
__device__ __forceinline__ float bfhi(unsigned u){ return __builtin_bit_cast(float, u & 0xffff0000u); }

// ---------------------------------------------------------------------------
// fg: F = emb@W1a + c, G = emb@W1b over all nodes. One 32-node tile per wave,
// 4 waves (128 nodes) per block. Per-block prologue builds the bf16 transposed
// W1[0:256] in LDS and the c vector (both from L2-hot W1).
//   A (emb rows, streamed):  lane holds A[m=lane&31][k=(lane>>5)*8+j]
//   B (sW from LDS):         lane holds B[k=(lane>>5)*8+j][n=lane&31]
//   C/D:                     col(n)=lane&31, row(m)=(r&3)+8*(r>>2)+4*(lane>>5)
// launch_bounds(256,3): 170-VGPR budget — (256,4) caps at 128 and spills (R6 lesson).
__global__ __launch_bounds__(256, 3) void fg_kernel(
    const float* __restrict__ embed, const float* __restrict__ W1,
    const float* __restrict__ b1, const int* __restrict__ srcp,
    const int* __restrict__ dstp, u16* __restrict__ F, u16* __restrict__ G, int NN)
{
  __shared__ __align__(16) u16 sW[64 * WSTR];
  __shared__ float sC[64];
  __shared__ float sRed[256];
  int tid = threadIdx.x;

  // --- prologue A: transpose W1[0:256][0:64] fp32 -> sW[n][k] bf16 (L2-hot) ---
  #pragma unroll
  for (int i = 0; i < 16; ++i){
    int idx = i * 256 + tid;               // 4096 float4 reads, fully coalesced
    int k = idx >> 4, q = idx & 15;
    float4 v = *(const float4*)(W1 + k * 64 + q * 4);
    sW[(4*q+0) * WSTR + k] = (u16)bfbits(v.x);
    sW[(4*q+1) * WSTR + k] = (u16)bfbits(v.y);
    sW[(4*q+2) * WSTR + k] = (u16)bfbits(v.z);
    sW[(4*q+3) * WSTR + k] = (u16)bfbits(v.w);
  }
  // --- prologue B: c partials, 4-way k-split across the block ---
  {
    int h = tid & 63, part = tid >> 6;
    int si = srcp[0], di = dstp[0];
    const float* se  = embed + (size_t)si * 128 + part * 32;
    const float* de  = embed + (size_t)di * 128 + part * 32;
    const float* w1s = W1 + (256 + part * 32) * 64 + h;
    const float* w1d = W1 + (384 + part * 32) * 64 + h;
    float acc = 0.f;
    #pragma unroll 8
    for (int k = 0; k < 32; ++k){
      acc += se[k] * w1s[k * 64];
      acc += de[k] * w1d[k * 64];
    }
    sRed[tid] = acc;
  }
  __syncthreads();
  if (tid < 64) sC[tid] = b1[tid] + sRed[tid] + sRed[64+tid] + sRed[128+tid] + sRed[192+tid];
  __syncthreads();

  // --- main MFMA loop ---
  int lane = tid & 63, wave = tid >> 6;
  int nl = lane & 31, h5 = lane >> 5;
  int tile = blockIdx.x * 128 + wave * 32;
  if (tile >= NN) return;                      // NN % 32 == 0; barriers already passed
  const float* erow = embed + (size_t)(tile + nl) * 128;
  f32x16 aF0 = Z16, aF1 = Z16, aG0 = Z16, aG1 = Z16;
  const u16* sw0 = sW + nl * WSTR;             // hidden rows 0..31
  const u16* sw1 = sW + (32 + nl) * WSTR;      // hidden rows 32..63
  #pragma unroll
  for (int s = 0; s < 8; ++s){                 // K = 128, 16 per MFMA
    int ko = s * 16 + h5 * 8;
    float4 x = *(const float4*)(erow + ko);
    float4 y = *(const float4*)(erow + ko + 4);
    uint4 u; u.x = pk2(x.x,x.y); u.y = pk2(x.z,x.w); u.z = pk2(y.x,y.y); u.w = pk2(y.z,y.w);
    bf16x8 a = __builtin_bit_cast(bf16x8, u);
    bf16x8 bF0 = *(const bf16x8*)(sw0 + ko);
    bf16x8 bF1 = *(const bf16x8*)(sw1 + ko);
    bf16x8 bG0 = *(const bf16x8*)(sw0 + 128 + ko);   // W1b at k=128..255
    bf16x8 bG1 = *(const bf16x8*)(sw1 + 128 + ko);
    aF0 = __builtin_amdgcn_mfma_f32_32x32x16_bf16(a, bF0, aF0, 0, 0, 0);
    aF1 = __builtin_amdgcn_mfma_f32_32x32x16_bf16(a, bF1, aF1, 0, 0, 0);
    aG0 = __builtin_amdgcn_mfma_f32_32x32x16_bf16(a, bG0, aG0, 0, 0, 0);
    aG1 = __builtin_amdgcn_mfma_f32_32x32x16_bf16(a, bG1, aG1, 0, 0, 0);
  }
  // --- epilogue: shfl_xor pair-pack cols; lane parity picks row r / r+1.
  // 4 u32 stores per r-pair (256B/instr across wave), bit-identical to scalar.
  float cv0 = sC[nl], cv1 = sC[32 + nl];
  int lo = lane & 1;
  int nlp = nl & ~1;                           // paired col base (u16 units)
  #pragma unroll
  for (int r = 0; r < 16; r += 2){
    int ra = r + lo;                           // row this lane stores
    int node = tile + (ra & 3) + 8 * (ra >> 2) + 4 * h5;
    u16* fr = F + (size_t)node * 64 + nlp;
    u16* gr = G + (size_t)node * 64 + nlp;
    float f0a = aF0[r]   + cv0;
    float f0b = aF0[r+1] + cv0;
    float f0an = __shfl_xor(f0a, 1), f0bn = __shfl_xor(f0b, 1);
    *(unsigned*)(fr)      = lo ? pk2(f0bn, f0b) : pk2(f0a, f0an);
    float f1a = aF1[r]   + cv1;
    float f1b = aF1[r+1] + cv1;
    float f1an = __shfl_xor(f1a, 1), f1bn = __shfl_xor(f1b, 1);
    *(unsigned*)(fr + 32) = lo ? pk2(f1bn, f1b) : pk2(f1a, f1an);
    float g0a = aG0[r], g0b = aG0[r+1];
    float g0an = __shfl_xor(g0a, 1), g0bn = __shfl_xor(g0b, 1);
    *(unsigned*)(gr)      = lo ? pk2(g0bn, g0b) : pk2(g0a, g0an);
    float g1a = aG1[r], g1b = aG1[r+1];
    float g1an = __shfl_xor(g1a, 1), g1bn = __shfl_xor(g1b, 1);
    *(unsigned*)(gr + 32) = lo ? pk2(g1bn, g1b) : pk2(g1a, g1an);
  }
}

// ---------------------------------------------------------------------------
// edge (R8 shape): 8 lanes per edge, lane j reads 16 B chunk j of the 128 B F/G
// row (8 merged line-requests per gather instruction). ONE octet per wave, no
// loop — 50K waves of minimal work; TLP hides the gather latency.
__global__ __launch_bounds__(256, 8) void edge_kernel(
    const u16* __restrict__ Ft, const u16* __restrict__ Gt,
    const float* __restrict__ W2, const float* __restrict__ b2,
    const float* __restrict__ noise, const int* __restrict__ col,
    const int* __restrict__ row, float* __restrict__ out, int E)
{
  int tid = threadIdx.x;
  int lane = tid & 63, wave = tid >> 6;
  int j = lane & 7, grp = lane >> 3;
  int e0 = blockIdx.x * 32 + wave * 8;
  if (e0 >= E) return;                         // wave-uniform
  int e = e0 + grp; if (e >= E) e = E - 1;     // clamp (safe read), store masked below
  int ci = col[e], ri = row[e];
  uint4 fv = ((const uint4*)(Ft + (size_t)ci * 64))[j];
  uint4 gv = ((const uint4*)(Gt + (size_t)ri * 64))[j];
  float4 w2a = ((const float4*)W2)[2 * j];
  float4 w2b = ((const float4*)W2)[2 * j + 1];
  float p = 0.f, h;
  h = fmaxf(bflo(fv.x) + bflo(gv.x), 0.f); p += h * w2a.x;
  h = fmaxf(bfhi(fv.x) + bfhi(gv.x), 0.f); p += h * w2a.y;
  h = fmaxf(bflo(fv.y) + bflo(gv.y), 0.f); p += h * w2a.z;
  h = fmaxf(bfhi(fv.y) + bfhi(gv.y), 0.f); p += h * w2a.w;
  h = fmaxf(bflo(fv.z) + bflo(gv.z), 0.f); p += h * w2b.x;
  h = fmaxf(bfhi(fv.z) + bfhi(gv.z), 0.f); p += h * w2b.y;
  h = fmaxf(bflo(fv.w) + bflo(gv.w), 0.f); p += h * w2b.z;
  h = fmaxf(bfhi(fv.w) + bfhi(gv.w), 0.f); p += h * w2b.w;
  p += __shfl_xor(p, 1, 64);
  p += __shfl_xor(p, 2, 64);
  p += __shfl_xor(p, 4, 64);
  if (j == 0 && e0 + grp < E){
    float ns = noise[e];
    float g = logf(ns) - log1pf(-ns) + p + b2[0];
    out[e] = 1.f / (1.f + expf(-g));
  }
}

// ---------------------------------------------------------------------------
// Insurance path if ws_size is too small for F/G tables: correct-but-slow fp32.
__global__ void naive_kernel(const float* __restrict__ embed, const float* __restrict__ W1,
    const float* __restrict__ b1, const float* __restrict__ W2, const float* __restrict__ b2,
    const float* __restrict__ noise, const int* __restrict__ col, const int* __restrict__ row,
    const int* __restrict__ srcp, const int* __restrict__ dstp, float* __restrict__ out, int E)
{
  int e = blockIdx.x * 256 + threadIdx.x;
  if (e >= E) return;
  int ci = col[e], ri = row[e], si = srcp[0], di = dstp[0];
  const float* ce = embed + (size_t)ci * 128;
  const float* re = embed + (size_t)ri * 128;
  const float* se = embed + (size_t)si * 128;
  const float* de = embed + (size_t)di * 128;
  float w = b2[0];
  for (int jj = 0; jj < 64; ++jj){
    float hh = b1[jj];
    for (int k = 0; k < 128; ++k){
      hh += ce[k] * W1[k * 64 + jj] + re[k] * W1[(128 + k) * 64 + jj]
          + se[k] * W1[(256 + k) * 64 + jj] + de[k] * W1[(384 + k) * 64 + jj];
    }
    w += fmaxf(hh, 0.f) * W2[jj];
  }
  float ns = noise[e];
  float g = logf(ns) - log1pf(-ns) + w;
  out[e] = 1.f / (1.f + expf(-g));
}

// ---------------------------------------------------------------------------
extern "C" void kernel_launch(void* const* d_in, const int* in_sizes, int n_in,
                              void* d_out, int out_size, void* d_ws, size_t ws_size,
                              hipStream_t stream)
{
  const float* embed = (const float*)d_in[0];
  const float* W1    = (const float*)d_in[1];
  const float* b1    = (const float*)d_in[2];
  const float* W2    = (const float*)d_in[3];
  const float* b2    = (const float*)d_in[4];
  const float* noise = (const float*)d_in[5];
  const int*   col   = (const int*)d_in[6];
  const int*   rowp  = (const int*)d_in[7];
  const int*   srcp  = (const int*)d_in[8];
  const int*   dstp  = (const int*)d_in[9];
  const int E  = in_sizes[5];
  const int NN = in_sizes[0] / 128;
  float* out = (float*)d_out;

  const size_t fBytes = (size_t)NN * 64 * sizeof(u16);
  if (ws_size >= 2 * fBytes){
    u16* F = (u16*)d_ws;
    u16* G = (u16*)((char*)d_ws + fBytes);
    fg_kernel<<<(NN + 127) / 128, 256, 0, stream>>>(embed, W1, b1, srcp, dstp, F, G, NN);
    edge_kernel<<<(E + 31) / 32, 256, 0, stream>>>(F, G, W2, b2, noise, col, rowp, out, E);
  } else {
    naive_kernel<<<(E + 255) / 256, 256, 0, stream>>>(embed, W1, b1, W2, b2, noise,
                                                      col, rowp, srcp, dstp, out, E);
  }
}